// Round 10
// baseline (130.951 us; speedup 1.0000x reference)
//
#include <hip/hip_runtime.h>

// UpsampleRFFT (zero-insert 2x + ideal half-band low-pass, circular), closed form:
//   g[j] = sign*cot(pi*(2j+1)/256)/128, sign=+ if j even
//   out[2r][2i]   = x[r][i] (exact fp32)      out[2r][2i+1] = T[r][i],  T = X*G
//   out[2p+1][c]  = sum_m g[(p-m)&127] * E[m][c],  E = even rows
// 2 blocks per image (output-column halves), LDS = 34.8KB. Phase A: T via MFMA
// (row-resident X), E^T (bf16) to LDS. Phase B: odd = G*E from LDS.
//
// R5-R7 lesson (rule #20): runtime-indexed register arrays -> scratch. All frag
// indices are compile-time; runtime offsets (cb, w) folded into LOAD ADDRESSES.
// R9: even-row global stores moved AFTER the barrier (pre-barrier stores forced
// s_waitcnt vmcnt(0) drain at s_barrier -> whole-block stall); all output
// stores nontemporal (write-once data, keep L2 for x/ghtab). R9 compile fix:
// nontemporal builtin needs ext_vector pointers (f32x4), not HIP float4.

typedef __bf16 bf16x8 __attribute__((ext_vector_type(8)));
typedef float  f32x4  __attribute__((ext_vector_type(4)));

#define W2 136        // Et pitch in bf16: 272B rows, 16B-aligned
#define PI_F 3.14159265358979323846f

__device__ __forceinline__ unsigned short f2bf(float x) {
    unsigned int b = __float_as_uint(x);
    return (unsigned short)((b + 0x7FFFu + ((b >> 16) & 1u)) >> 16);  // RNE
}

__device__ __forceinline__ float gfun(int j) {           // g[j & 127]
    int d = 2 * (j & 127) + 1;
    float th = PI_F * (float)d * (1.0f / 256.0f);
    float s  = ((d & 3) == 1) ? 1.0f : -1.0f;
    return s * cosf(th) / (128.0f * sinf(th));
}

// ---- init: per-lane tap fragment table (8 frags x 64 lanes x 8 bf16 = 8KB) ----
__global__ __launch_bounds__(512)
void init_ghtab(unsigned short* __restrict__ ghtab)
{
    const int t    = threadIdx.x;         // t = dd*64 + lane
    const int lane = t & 63;
    const int l15  = lane & 15;
    const int l4   = lane >> 4;
    const int dd   = t >> 6;
    const int base = l15 - 8 * l4 + 16 * dd;
    unsigned short u[8];
    #pragma unroll
    for (int e = 0; e < 8; ++e) u[e] = f2bf(gfun(base - e));
    *(ushort4*)&ghtab[t * 8]     = make_ushort4(u[0], u[1], u[2], u[3]);
    *(ushort4*)&ghtab[t * 8 + 4] = make_ushort4(u[4], u[5], u[6], u[7]);
}

// ---- fused kernel: 2 blocks/image (c-halves), 512 threads (8 waves) ----
__global__ __launch_bounds__(512, 4)
void upsample_fused(const float* __restrict__ xin, float* __restrict__ out,
                    const unsigned short* __restrict__ ghtab)
{
    __shared__ __align__(16) unsigned short Et[128 * W2]; // Et[c_loc][r], bf16 bits

    const int tid  = threadIdx.x;
    const int lane = tid & 63;
    const int w    = tid >> 6;        // 0..7: r-tile (A) and p-tile (B)
    const int l15  = lane & 15;
    const int l4   = lane >> 4;

    const long long img = blockIdx.x >> 1;
    const int cb        = blockIdx.x & 1;          // column half
    const float* __restrict__ xim = xin + img * (128LL * 128LL);
    float*       __restrict__ oim = out + img * (256LL * 256LL);

    const int r = 16 * w + l15;
    const float* __restrict__ xrow = xim + r * 128;

    // issue full-row x loads first (K=128 needed for the W-conv)
    float4 xlo[4], xhi[4];
    #pragma unroll
    for (int t = 0; t < 4; ++t) {
        xlo[t] = *(const float4*)&xrow[32 * t + 8 * l4];
        xhi[t] = *(const float4*)&xrow[32 * t + 8 * l4 + 4];
    }

    // Phase-A tap frags: cb folded into the ADDRESS; register indices static.
    // ghc[v] = frag[(v + 4cb) & 7].
    bf16x8 ghc[8];
    #pragma unroll
    for (int v = 0; v < 8; ++v) {
        const int dd = (v + 4 * cb) & 7;
        ghc[v] = *(const bf16x8*)&ghtab[(dd * 64 + lane) * 8];
    }

    // X fragments (transient union, register-resident) + even cols of E^T.
    bf16x8 xa[4];
    #pragma unroll
    for (int t = 0; t < 4; ++t) {
        union { bf16x8 v; unsigned short u[8]; } H;
        H.u[0] = f2bf(xlo[t].x); H.u[1] = f2bf(xlo[t].y);
        H.u[2] = f2bf(xlo[t].z); H.u[3] = f2bf(xlo[t].w);
        H.u[4] = f2bf(xhi[t].x); H.u[5] = f2bf(xhi[t].y);
        H.u[6] = f2bf(xhi[t].z); H.u[7] = f2bf(xhi[t].w);
        xa[t] = H.v;
        if ((t >> 1) == cb) {                      // this t covers our c-half
            const int tt = t & 1;
            #pragma unroll
            for (int e = 0; e < 8; ++e)
                Et[(64 * tt + 16 * l4 + 2 * e) * W2 + r] = H.u[e];
        }
    }

    // ---- phase A: T = X*G (transposed). LDS writes only; accs stay in regs,
    // global stores deferred past the barrier (no vmcnt drain at s_barrier). ----
    f32x4 acc[4];
    #pragma unroll
    for (int mt = 0; mt < 4; ++mt) {
        f32x4 a = {0.f, 0.f, 0.f, 0.f};
        #pragma unroll
        for (int t = 0; t < 4; ++t)
            a = __builtin_amdgcn_mfma_f32_16x16x32_bf16(ghc[(mt - 2 * t) & 7],
                                                        xa[t], a, 0, 0, 0);
        acc[mt] = a;
        const int i0l = 16 * mt + 4 * l4;          // local i in [0,64)
        #pragma unroll
        for (int q = 0; q < 4; ++q)
            Et[(2 * (i0l + q) + 1) * W2 + r] = f2bf(a[q]);
    }
    __syncthreads();

    // Phase-B per-wave B-frags: runtime ADDRESS, static indices (L2-hit).
    bf16x8 gb[4];
    #pragma unroll
    for (int t = 0; t < 4; ++t) {
        const int dd = (w - 2 * t) & 7;
        gb[t] = *(const bf16x8*)&ghtab[(dd * 64 + lane) * 8];
    }

    // ---- even output rows: stores fly concurrently with phase B compute ----
    float* __restrict__ orow = oim + (2 * r) * 256 + 128 * cb;
    #pragma unroll
    for (int mt = 0; mt < 4; ++mt) {
        const int i0l = 16 * mt + 4 * l4;
        float4 xc = *(const float4*)&xrow[64 * cb + i0l];   // L1/L2 hit, exact fp32
        f32x4 o0 = {xc.x, acc[mt][0], xc.y, acc[mt][1]};
        f32x4 o1 = {xc.z, acc[mt][2], xc.w, acc[mt][3]};
        __builtin_nontemporal_store(o0, (f32x4*)&orow[2 * i0l]);
        __builtin_nontemporal_store(o1, (f32x4*)&orow[2 * i0l + 4]);
    }

    // ---- phase B: odd[p][c] = sum_m g[(p-m)&127] * E[m][c] ----
    {
        float* __restrict__ prow = oim + (2 * (16 * w + l15) + 1) * 256 + 128 * cb;
        #pragma unroll
        for (int mc = 0; mc < 8; ++mc) {
            f32x4 a = {0.f, 0.f, 0.f, 0.f};
            #pragma unroll
            for (int t = 0; t < 4; ++t) {
                bf16x8 ef = *(const bf16x8*)&Et[(16 * mc + l15) * W2 + 32 * t + 8 * l4];
                a = __builtin_amdgcn_mfma_f32_16x16x32_bf16(ef, gb[t], a, 0, 0, 0);
            }
            __builtin_nontemporal_store(a, (f32x4*)&prow[16 * mc + 4 * l4]);
        }
    }
}

extern "C" void kernel_launch(void* const* d_in, const int* in_sizes, int n_in,
                              void* d_out, int out_size, void* d_ws, size_t ws_size,
                              hipStream_t stream)
{
    (void)n_in; (void)out_size; (void)ws_size;
    const float* x = (const float*)d_in[0];
    float* out = (float*)d_out;
    int nimg = in_sizes[0] / (128 * 128);   // 1024 images

    unsigned short* ghtab = (unsigned short*)d_ws;   // needs 8KB; ws is ample
    hipLaunchKernelGGL(init_ghtab, dim3(1), dim3(512), 0, stream, ghtab);
    hipLaunchKernelGGL(upsample_fused, dim3(nimg * 2), dim3(512), 0, stream, x, out, ghtab);
}

// Round 11
// 99.372 us; speedup vs baseline: 1.3178x; 1.3178x over previous
//
#include <hip/hip_runtime.h>

// UpsampleRFFT (zero-insert 2x + ideal half-band low-pass, circular), closed form:
//   g[j] = sign*cot(pi*(2j+1)/256)/128, sign=+ if j even
//   out[2r][2i]   = x[r][i] (exact fp32)      out[2r][2i+1] = T[r][i],  T = X*G
//   out[2p+1][c]  = sum_m g[(p-m)&127] * E[m][c],  E = even rows
// 2 blocks per image (output-column halves), LDS = 34.8KB -> 4 blocks/CU.
// Phase A: T via MFMA (row-resident X), even rows stored in-loop (R8-proven),
// E^T (bf16) to LDS. Phase B: odd = G*E from LDS.
//
// R5-R7 lesson (rule #20): runtime-indexed register arrays -> scratch. All frag
// indices are compile-time; runtime offsets (cb, w) folded into LOAD ADDRESSES.
// R10 lesson: nontemporal stores regressed (-35%): 64B-granular phase-B store
// fragments need L2 write-coalescing; nt bypasses L2 -> partial-line HBM RMW.
// Deferred-past-barrier stores also not needed (4 blocks/CU covers the drain).
// R11: same-XCD pairing of each image's two c-half blocks (bid and bid+8 are
// the same image) so the duplicated x-row reads hit the pair's shared L2.

typedef __bf16 bf16x8 __attribute__((ext_vector_type(8)));
typedef float  f32x4  __attribute__((ext_vector_type(4)));

#define W2 136        // Et pitch in bf16: 272B rows, 16B-aligned
#define PI_F 3.14159265358979323846f

__device__ __forceinline__ unsigned short f2bf(float x) {
    unsigned int b = __float_as_uint(x);
    return (unsigned short)((b + 0x7FFFu + ((b >> 16) & 1u)) >> 16);  // RNE
}

__device__ __forceinline__ float gfun(int j) {           // g[j & 127]
    int d = 2 * (j & 127) + 1;
    float th = PI_F * (float)d * (1.0f / 256.0f);
    float s  = ((d & 3) == 1) ? 1.0f : -1.0f;
    return s * cosf(th) / (128.0f * sinf(th));
}

// ---- init: per-lane tap fragment table (8 frags x 64 lanes x 8 bf16 = 8KB) ----
__global__ __launch_bounds__(512)
void init_ghtab(unsigned short* __restrict__ ghtab)
{
    const int t    = threadIdx.x;         // t = dd*64 + lane
    const int lane = t & 63;
    const int l15  = lane & 15;
    const int l4   = lane >> 4;
    const int dd   = t >> 6;
    const int base = l15 - 8 * l4 + 16 * dd;
    unsigned short u[8];
    #pragma unroll
    for (int e = 0; e < 8; ++e) u[e] = f2bf(gfun(base - e));
    *(ushort4*)&ghtab[t * 8]     = make_ushort4(u[0], u[1], u[2], u[3]);
    *(ushort4*)&ghtab[t * 8 + 4] = make_ushort4(u[4], u[5], u[6], u[7]);
}

// ---- fused kernel: 2 blocks/image (c-halves), 512 threads (8 waves) ----
__global__ __launch_bounds__(512, 4)
void upsample_fused(const float* __restrict__ xin, float* __restrict__ out,
                    const unsigned short* __restrict__ ghtab)
{
    __shared__ __align__(16) unsigned short Et[128 * W2]; // Et[c_loc][r], bf16 bits

    const int tid  = threadIdx.x;
    const int lane = tid & 63;
    const int w    = tid >> 6;        // 0..7: r-tile (A) and p-tile (B)
    const int l15  = lane & 15;
    const int l4   = lane >> 4;

    // Same-XCD pairing: blocks bid and bid+8 are the two c-halves of one image;
    // both ≡ bid (mod 8) -> same XCD -> second x read is an L2 hit.
    const int bid = blockIdx.x;
    const long long img = (long long)((bid & 7) | ((bid >> 4) << 3));
    const int cb        = (bid >> 3) & 1;          // column half
    const float* __restrict__ xim = xin + img * (128LL * 128LL);
    float*       __restrict__ oim = out + img * (256LL * 256LL);

    const int r = 16 * w + l15;
    const float* __restrict__ xrow = xim + r * 128;

    // issue full-row x loads first (K=128 needed for the W-conv)
    float4 xlo[4], xhi[4];
    #pragma unroll
    for (int t = 0; t < 4; ++t) {
        xlo[t] = *(const float4*)&xrow[32 * t + 8 * l4];
        xhi[t] = *(const float4*)&xrow[32 * t + 8 * l4 + 4];
    }

    // Phase-A tap frags: cb folded into the ADDRESS; register indices static.
    // ghc[v] = frag[(v + 4cb) & 7].
    bf16x8 ghc[8];
    #pragma unroll
    for (int v = 0; v < 8; ++v) {
        const int dd = (v + 4 * cb) & 7;
        ghc[v] = *(const bf16x8*)&ghtab[(dd * 64 + lane) * 8];
    }

    // X fragments (transient union, register-resident) + even cols of E^T.
    bf16x8 xa[4];
    #pragma unroll
    for (int t = 0; t < 4; ++t) {
        union { bf16x8 v; unsigned short u[8]; } H;
        H.u[0] = f2bf(xlo[t].x); H.u[1] = f2bf(xlo[t].y);
        H.u[2] = f2bf(xlo[t].z); H.u[3] = f2bf(xlo[t].w);
        H.u[4] = f2bf(xhi[t].x); H.u[5] = f2bf(xhi[t].y);
        H.u[6] = f2bf(xhi[t].z); H.u[7] = f2bf(xhi[t].w);
        xa[t] = H.v;
        if ((t >> 1) == cb) {                      // this t covers our c-half
            const int tt = t & 1;
            #pragma unroll
            for (int e = 0; e < 8; ++e)
                Et[(64 * tt + 16 * l4 + 2 * e) * W2 + r] = H.u[e];
        }
    }

    // ---- phase A: T = X*G (transposed); even output rows + odd cols of E^T ----
    float* __restrict__ orow = oim + (2 * r) * 256 + 128 * cb;
    #pragma unroll
    for (int mt = 0; mt < 4; ++mt) {
        f32x4 acc = {0.f, 0.f, 0.f, 0.f};
        #pragma unroll
        for (int t = 0; t < 4; ++t)
            acc = __builtin_amdgcn_mfma_f32_16x16x32_bf16(ghc[(mt - 2 * t) & 7],
                                                          xa[t], acc, 0, 0, 0);
        const int i0l = 16 * mt + 4 * l4;          // local i in [0,64)
        float4 xc = *(const float4*)&xrow[64 * cb + i0l];   // L1 hit, exact fp32
        float4 o0 = make_float4(xc.x, acc[0], xc.y, acc[1]);
        float4 o1 = make_float4(xc.z, acc[2], xc.w, acc[3]);
        *(float4*)&orow[2 * i0l]     = o0;
        *(float4*)&orow[2 * i0l + 4] = o1;
        #pragma unroll
        for (int q = 0; q < 4; ++q)
            Et[(2 * (i0l + q) + 1) * W2 + r] = f2bf(acc[q]);
    }
    __syncthreads();

    // ---- phase B: odd[p][c] = sum_m g[(p-m)&127] * E[m][c] ----
    {
        // Per-wave B-frags loaded at runtime-computed ADDRESSES (indices static).
        bf16x8 gb[4];
        #pragma unroll
        for (int t = 0; t < 4; ++t) {
            const int dd = (w - 2 * t) & 7;
            gb[t] = *(const bf16x8*)&ghtab[(dd * 64 + lane) * 8];
        }
        float* __restrict__ prow = oim + (2 * (16 * w + l15) + 1) * 256 + 128 * cb;
        #pragma unroll
        for (int mc = 0; mc < 8; ++mc) {
            f32x4 acc = {0.f, 0.f, 0.f, 0.f};
            #pragma unroll
            for (int t = 0; t < 4; ++t) {
                bf16x8 ef = *(const bf16x8*)&Et[(16 * mc + l15) * W2 + 32 * t + 8 * l4];
                acc = __builtin_amdgcn_mfma_f32_16x16x32_bf16(ef, gb[t], acc, 0, 0, 0);
            }
            float4 o = make_float4(acc[0], acc[1], acc[2], acc[3]);
            *(float4*)&prow[16 * mc + 4 * l4] = o;   // p=16w+l15, c=16mc+4l4+q
        }
    }
}

extern "C" void kernel_launch(void* const* d_in, const int* in_sizes, int n_in,
                              void* d_out, int out_size, void* d_ws, size_t ws_size,
                              hipStream_t stream)
{
    (void)n_in; (void)out_size; (void)ws_size;
    const float* x = (const float*)d_in[0];
    float* out = (float*)d_out;
    int nimg = in_sizes[0] / (128 * 128);   // 1024 images

    unsigned short* ghtab = (unsigned short*)d_ws;   // needs 8KB; ws is ample
    hipLaunchKernelGGL(init_ghtab, dim3(1), dim3(512), 0, stream, ghtab);
    hipLaunchKernelGGL(upsample_fused, dim3(nimg * 2), dim3(512), 0, stream, x, out, ghtab);
}